// Round 8
// baseline (377.909 us; speedup 1.0000x reference)
//
#include <hip/hip_runtime.h>

// Problem: B=2048, H=4, D=4096, M=8, dm=512.
// s_flat[r,j] = sum_h x[b,h,m*512+c]*lW[m,h] + lb[m],
//   m=r>>8, b=(r&255)*8+(j>>9), c=j&511.
// out[r,n] = sigmoid(sum_j s_flat[r,j]*pW[n,j] + pb[n]),  out fp32 [2048][4096].
//
// R12: prep = v3-exact (five access-pattern variants all ~87 us -> parked).
// GEMM theory rebuilt from R5-R9 data: time tracks STAGED L2/L3 BYTES, not
// schedule (R9's different pipeline = same 87 us; fp32-B always +55-100 us).
// B-panel logical = (M/BM) x 32 MiB crosses XCDs (L3/fabric-served): at
// BM=128 that's 512 MiB / 82 us = 6.2 TB/s ~= the observed service ceiling.
// => BM=256, BN=128 halves L3-crossing B traffic (512 -> 256 MiB).
//   grid 256 (1 block/CU), 4 waves, wave-tile 128x64 (32 frags),
//   LDS 96 KiB dbuf, single-barrier issue-early loop (R6-proven structure --
//   needed since 1 block/CU has no partner block to hide staging).
//   XCD swizzle: XCD j owns wg [32j,32j+32) = one full r-panel -> A-panel
//   (2 MiB bf16) is XCD-L2-resident; only B crosses.
// Same f2bf, same MFMA shapes, same per-output accumulation order ->
// bit-identical output.

#define MD 2048
#define ND 4096
#define KD 4096

typedef __attribute__((ext_vector_type(8))) __bf16 bf16x8;
typedef __attribute__((ext_vector_type(4))) float f32x4;

static __device__ __forceinline__ unsigned short f2bf(float f) {
  union { float f; unsigned int u; } v; v.f = f;
  unsigned int u = v.u;
  u += 0x7FFFu + ((u >> 16) & 1u);   // RNE
  return (unsigned short)(u >> 16);
}

// Prep v3 (R0/R8-exact): one-shot threads, 8x16B loads in flight, plain
// cacheable loads, 16B stores.
// blocks [0,4096): s_flat (bf16), 8 j's per thread.
// blocks [4096,8192): proj_W fp32 -> bf16, 16 floats per thread.
__global__ __launch_bounds__(256) void prep_kernel(
    const float* __restrict__ x, const float* __restrict__ lW,
    const float* __restrict__ lb, const float* __restrict__ pW,
    unsigned short* __restrict__ sB, unsigned short* __restrict__ wB) {
  int bid = blockIdx.x;
  int tid = threadIdx.x;
  if (bid < 4096) {
    int g = bid * 256 + tid;                  // 0 .. 2^20
    int j8 = g << 3;                          // flat index r*4096 + j, j8 % 8 == 0
    int r = j8 >> 12;
    int j = j8 & 4095;
    int m = r >> 8;
    int b = ((r & 255) << 3) + (j >> 9);
    int c = j & 511;                          // 8 consecutive j stay in one 512-group
    const float* xp = x + ((long)b << 14) + m * 512 + c;
    float w0 = lW[m * 4 + 0], w1 = lW[m * 4 + 1], w2 = lW[m * 4 + 2], w3 = lW[m * 4 + 3];
    float bb = lb[m];
    float4 xa0 = *(const float4*)(xp);
    float4 xb0 = *(const float4*)(xp + 4);
    float4 xa1 = *(const float4*)(xp + 4096);
    float4 xb1 = *(const float4*)(xp + 4100);
    float4 xa2 = *(const float4*)(xp + 8192);
    float4 xb2 = *(const float4*)(xp + 8196);
    float4 xa3 = *(const float4*)(xp + 12288);
    float4 xb3 = *(const float4*)(xp + 12292);
    float v0 = bb + xa0.x * w0 + xa1.x * w1 + xa2.x * w2 + xa3.x * w3;
    float v1 = bb + xa0.y * w0 + xa1.y * w1 + xa2.y * w2 + xa3.y * w3;
    float v2 = bb + xa0.z * w0 + xa1.z * w1 + xa2.z * w2 + xa3.z * w3;
    float v3 = bb + xa0.w * w0 + xa1.w * w1 + xa2.w * w2 + xa3.w * w3;
    float v4 = bb + xb0.x * w0 + xb1.x * w1 + xb2.x * w2 + xb3.x * w3;
    float v5 = bb + xb0.y * w0 + xb1.y * w1 + xb2.y * w2 + xb3.y * w3;
    float v6 = bb + xb0.z * w0 + xb1.z * w1 + xb2.z * w2 + xb3.z * w3;
    float v7 = bb + xb0.w * w0 + xb1.w * w1 + xb2.w * w2 + xb3.w * w3;
    uint4 pk;
    pk.x = (unsigned)f2bf(v0) | ((unsigned)f2bf(v1) << 16);
    pk.y = (unsigned)f2bf(v2) | ((unsigned)f2bf(v3) << 16);
    pk.z = (unsigned)f2bf(v4) | ((unsigned)f2bf(v5) << 16);
    pk.w = (unsigned)f2bf(v6) | ((unsigned)f2bf(v7) << 16);
    *(uint4*)(sB + j8) = pk;                  // 16B store
  } else {
    int g = (bid - 4096) * 256 + tid;         // 0 .. 2^20, x16 floats
    long off = (long)g << 4;
    float4 a = *(const float4*)(pW + off);
    float4 b4 = *(const float4*)(pW + off + 4);
    float4 c4 = *(const float4*)(pW + off + 8);
    float4 d4 = *(const float4*)(pW + off + 12);
    uint4 p0, p1;
    p0.x = (unsigned)f2bf(a.x) | ((unsigned)f2bf(a.y) << 16);
    p0.y = (unsigned)f2bf(a.z) | ((unsigned)f2bf(a.w) << 16);
    p0.z = (unsigned)f2bf(b4.x) | ((unsigned)f2bf(b4.y) << 16);
    p0.w = (unsigned)f2bf(b4.z) | ((unsigned)f2bf(b4.w) << 16);
    p1.x = (unsigned)f2bf(c4.x) | ((unsigned)f2bf(c4.y) << 16);
    p1.y = (unsigned)f2bf(c4.z) | ((unsigned)f2bf(c4.w) << 16);
    p1.z = (unsigned)f2bf(d4.x) | ((unsigned)f2bf(d4.y) << 16);
    p1.w = (unsigned)f2bf(d4.z) | ((unsigned)f2bf(d4.w) << 16);
    *(uint4*)(wB + off) = p0;
    *(uint4*)(wB + off + 8) = p1;
  }
}

// GEMM: C[2048][4096] = S[2048][4096] * W[4096][4096]^T (both bf16, K
// contiguous), epilogue sigmoid(acc + pb[n]) -> fp32.
// BM=256, BN=128, BK=64; 256 threads (4 waves 2x2); wave-tile 128x64
// (8x4 fragments of 16x16x32); grid 256 = 1 block/CU.
// LDS: As/Bs double-buffered, linear [row][64] ushorts, XOR 16B-chunk
// swizzle (phys chunk = kc ^ (row&7)) pre-applied to the per-lane GLOBAL
// source address (m173 pattern; byte-identical formulas to the proven R0
// kernel -- fragment reads 0 bank conflicts).
// Loop: single __syncthreads per K-tile; stage(t+1) issued right after the
// barrier, flies under the 64-MFMA compute phase, drained by the next
// barrier's implicit vmcnt(0).
#define BM 256
#define BN 128
#define BK 64

__global__ __launch_bounds__(256) void gemm_kernel(
    const unsigned short* __restrict__ S, const unsigned short* __restrict__ W,
    const float* __restrict__ pb, float* __restrict__ out) {
  __shared__ unsigned short As[2][BM * BK];   // 2 x 32 KiB
  __shared__ unsigned short Bs[2][BN * BK];   // 2 x 16 KiB   (96 KiB total)
  int tid = threadIdx.x;
  int lane = tid & 63;
  int wave = tid >> 6;

  // XCD swizzle: hw bid -> XCD bid%8; wg = (bid%8)*32 + bid/8 gives XCD j
  // the 32 contiguous wg of one full r-panel (A-panel 2 MiB -> L2-resident).
  // Bijective: 256 % 8 == 0.
  int bid = blockIdx.x;                      // 0..255
  int wg = ((bid & 7) << 5) + (bid >> 3);
  int r0 = (wg >> 5) << 8;                   // 8 r-panels * 256
  int n0 = (wg & 31) << 7;                   // 32 n-blocks * 128
  int wr = wave >> 1, wc = wave & 1;         // wave-tile 128x64

  // Staging: per issue i, rows i*32 + wave*8 + (lane>>3); phys chunk lane&7
  // holds global chunk (lane&7) ^ (row&7); row&7 == (lane>>3)&7.
  int srow = (wave << 3) + (lane >> 3);
  int scol = (((lane & 7) ^ (lane >> 3)) << 3);    // pre-swizzled k offset
  const unsigned short* gA = S + (long)(r0 + srow) * KD + scol;
  const unsigned short* gB = W + (long)(n0 + srow) * KD + scol;

#define STAGE(buf, tt) do {                                                    \
    const long ko_ = (long)(tt) * BK;                                          \
    _Pragma("unroll")                                                          \
    for (int i_ = 0; i_ < 8; ++i_)                                             \
      __builtin_amdgcn_global_load_lds(                                        \
          (const __attribute__((address_space(1))) unsigned int*)(gA + (long)i_ * 32 * KD + ko_), \
          (__attribute__((address_space(3))) unsigned int*)(&As[buf][(i_ * 32 + (wave << 3)) * BK]), 16, 0, 0); \
    _Pragma("unroll")                                                          \
    for (int i_ = 0; i_ < 4; ++i_)                                             \
      __builtin_amdgcn_global_load_lds(                                        \
          (const __attribute__((address_space(1))) unsigned int*)(gB + (long)i_ * 32 * KD + ko_), \
          (__attribute__((address_space(3))) unsigned int*)(&Bs[buf][(i_ * 32 + (wave << 3)) * BK]), 16, 0, 0); \
  } while (0)

  f32x4 acc[8][4] = {};

  STAGE(0, 0);   // prologue: tile 0 -> buf 0 (drained by first __syncthreads)

  for (int t = 0; t < KD / BK; ++t) {
    __syncthreads();   // drains stage(t) (vmcnt0) + all waves done with buf[(t-1)&1]
    if (t + 1 < KD / BK) STAGE((t + 1) & 1, t + 1);  // flies under MFMA(t)
    int cur = t & 1;
#pragma unroll
    for (int ks = 0; ks < 2; ++ks) {
      // fragment chunk kc_lin = ks*4 + (lane>>4); physical = kc_lin ^ (row&7);
      // row&7 == lane&7 for all fragment rows (offsets are 0 mod 8).
      int swz = (((ks << 2) + (lane >> 4)) ^ (lane & 7)) << 3;
      bf16x8 af[8], bfv[4];
#pragma unroll
      for (int mt = 0; mt < 8; ++mt)
        af[mt] = *(const bf16x8*)&As[cur][((wr << 7) + mt * 16 + (lane & 15)) * BK + swz];
#pragma unroll
      for (int nt = 0; nt < 4; ++nt)
        bfv[nt] = *(const bf16x8*)&Bs[cur][((wc << 6) + nt * 16 + (lane & 15)) * BK + swz];
#pragma unroll
      for (int mt = 0; mt < 8; ++mt)
#pragma unroll
        for (int nt = 0; nt < 4; ++nt)
          acc[mt][nt] = __builtin_amdgcn_mfma_f32_16x16x32_bf16(af[mt], bfv[nt], acc[mt][nt], 0, 0, 0);
    }
  }

  // epilogue: C/D layout col=lane&15, row=(lane>>4)*4+i  [m89/m91]
#pragma unroll
  for (int nt = 0; nt < 4; ++nt) {
    int col = n0 + (wc << 6) + nt * 16 + (lane & 15);
    float pbv = pb[col];
#pragma unroll
    for (int mt = 0; mt < 8; ++mt) {
      int row = r0 + (wr << 7) + mt * 16 + ((lane >> 4) << 2);
#pragma unroll
      for (int i = 0; i < 4; ++i) {
        float v = acc[mt][nt][i] + pbv;
        out[(long)(row + i) * ND + col] = 1.0f / (1.0f + __expf(-v));
      }
    }
  }
#undef STAGE
}

extern "C" void kernel_launch(void* const* d_in, const int* in_sizes, int n_in,
                              void* d_out, int out_size, void* d_ws, size_t ws_size,
                              hipStream_t stream) {
  const float* x  = (const float*)d_in[0];   // (2048, 4, 4096)
  const float* lW = (const float*)d_in[1];   // (8, 4)
  const float* lb = (const float*)d_in[2];   // (8,)
  const float* pW = (const float*)d_in[3];   // (4096, 4096)
  const float* pb = (const float*)d_in[4];   // (4096,)
  float* out = (float*)d_out;                // (2048, 4096) fp32

  unsigned short* sB = (unsigned short*)d_ws;          // 2048*4096 bf16 = 16 MiB
  unsigned short* wB = sB + (long)MD * KD;             // 4096*4096 bf16 = 32 MiB

  prep_kernel<<<8192, 256, 0, stream>>>(x, lW, lb, pW, sB, wB);
  gemm_kernel<<<256, 256, 0, stream>>>(sB, wB, pb, out);
}